// Round 13
// baseline (183.385 us; speedup 1.0000x reference)
//
#include <hip/hip_runtime.h>

// DescriptorMatcher match_snn — R4: TLP fix (8 waves/SIMD).
// R3 post-mortem: latency-bound (MfmaUtil 13 / VALUBusy 20 / occ 20%).
// R4: ROWS_PER_WAVE 64->16, __launch_bounds__(256,8) caps VGPR@64,
//     grid 2048 blocks = exactly 8 blocks/CU (single residency round),
//     plain loop (R3's pointer-passed dbuf regressed codegen — reverted).
// Core (proven R2, absmax 0.0): A pre-scaled by -2, acc init n2+COFF,
//     packed u = (bits(m') & 0xFFFFE000) | col ; top-2 via u32 min/max.

typedef __bf16 bf16x8 __attribute__((ext_vector_type(8)));
typedef __bf16 bf16x2 __attribute__((ext_vector_type(2)));
typedef float f32x4 __attribute__((ext_vector_type(4)));

#define NB 8192
#define DK 128
#define NCHUNK 16
#define CHUNK (NB / NCHUNK)   /* 512 cols per chunk */
#define JT (CHUNK / 16)       /* 32 col-tiles per chunk */
#define ROWS_PER_WAVE 16      /* one 16-row MFMA tile per wave */
#define BM 64                 /* 4 waves per block */
#define COFF 512.0f           /* positivity offset for packed ordering */
#define VMASK 0xFFFFE000u     /* keep sign+exp+10 mantissa bits; low 13 = col */

// --- fused convert: desc1 -> -2*bf16, n1 raw ; desc2 -> bf16, n2+COFF ------
__global__ __launch_bounds__(256) void conv_norm_kernel(const float* __restrict__ desc1,
                                                        const float* __restrict__ desc2,
                                                        __bf16* __restrict__ d1b,
                                                        __bf16* __restrict__ d2b,
                                                        float* __restrict__ n1,
                                                        float* __restrict__ n2pc) {
    const int idx  = blockIdx.x * 4 + (threadIdx.x >> 6); // one wave per row
    const int lane = threadIdx.x & 63;
    const bool is2 = idx >= NB;
    const int row  = is2 ? idx - NB : idx;
    const float* src = is2 ? desc2 : desc1;
    const size_t off = (size_t)row * DK + lane * 2;
    const float2 v = *reinterpret_cast<const float2*>(src + off);
    float s = v.x * v.x + v.y * v.y;
    const float sc = is2 ? 1.0f : -2.0f;
    bf16x2 bp;
    bp[0] = (__bf16)(v.x * sc);
    bp[1] = (__bf16)(v.y * sc);
    *reinterpret_cast<bf16x2*>((is2 ? d2b : d1b) + off) = bp;
#pragma unroll
    for (int d = 1; d < 64; d <<= 1) s += __shfl_xor(s, d);
    if (lane == 0) {
        if (is2) n2pc[row] = s + COFF;
        else     n1[row] = s;
    }
}

// --- main: wave owns 16 rows x 512-col chunk; fused GEMM + packed top-2 ----
__global__ __launch_bounds__(256, 8) void snn_main_kernel(const __bf16* __restrict__ d1b,
                                                          const __bf16* __restrict__ d2b,
                                                          const float* __restrict__ n2pc,
                                                          unsigned* __restrict__ pmin1,
                                                          unsigned* __restrict__ pmin2) {
    const int lane    = threadIdx.x & 63;
    const int wid     = threadIdx.x >> 6;
    const int rowbase = blockIdx.x * BM + wid * ROWS_PER_WAVE;
    const int colbase = blockIdx.y * CHUNK;
    const int lrow    = lane & 15;
    const int lk      = (lane >> 4) * 8;

    // A fragments (row = lane&15, k = (lane>>4)*8 + b) — A is pre-scaled by -2
    bf16x8 afrag[4];
#pragma unroll
    for (int kk = 0; kk < 4; ++kk)
        afrag[kk] = *reinterpret_cast<const bf16x8*>(
            d1b + (size_t)(rowbase + lrow) * DK + kk * 32 + lk);

    unsigned p1[4], p2[4];
#pragma unroll
    for (int e = 0; e < 4; ++e) { p1[e] = 0xFFFFFFFFu; p2[e] = 0xFFFFFFFFu; }

    const __bf16* bbase = d2b + (size_t)(colbase + lrow) * DK + lk;
    const float* n2p = n2pc + colbase + lrow;
    const unsigned colv = colbase + lrow;

    for (int jt = 0; jt < JT; ++jt) {
        const __bf16* bp = bbase + (size_t)jt * 16 * DK;
        bf16x8 bfrag[4];
#pragma unroll
        for (int kk = 0; kk < 4; ++kk)
            bfrag[kk] = *reinterpret_cast<const bf16x8*>(bp + kk * 32);
        const float n2c = n2p[jt * 16];      // per-lane col constant (col = lane&15)
        const unsigned col = colv + jt * 16;
        f32x4 acc = {n2c, n2c, n2c, n2c};    // exits loop = n2 + C - 2*dot
#pragma unroll
        for (int kk = 0; kk < 4; ++kk)
            acc = __builtin_amdgcn_mfma_f32_16x16x32_bf16(afrag[kk], bfrag[kk], acc, 0, 0, 0);
        // C/D layout: col = lane&15, row = (lane>>4)*4 + e
#pragma unroll
        for (int e = 0; e < 4; ++e) {
            const unsigned u = (__builtin_bit_cast(unsigned, acc[e]) & VMASK) | col;
            const unsigned t = max(p1[e], u);
            p1[e] = min(p1[e], u);
            p2[e] = min(p2[e], t);
        }
    }

    // cross-lane top-2 merge within each 16-lane group (same rows, diff cols)
#pragma unroll
    for (int e = 0; e < 4; ++e) {
        unsigned a1 = p1[e], a2 = p2[e];
#pragma unroll
        for (int d = 1; d <= 8; d <<= 1) {
            const unsigned o1 = __shfl_xor(a1, d);
            const unsigned o2 = __shfl_xor(a2, d);
            const unsigned t = max(a1, o1);
            a1 = min(a1, o1);
            a2 = min(min(a2, o2), t);
        }
        if (lrow == 0) {
            const int row = rowbase + (lane >> 4) * 4 + e;
            const size_t off = (size_t)blockIdx.y * NB + row;
            pmin1[off] = a1;
            pmin2[off] = a2;
        }
    }
}

// --- phase 2: merge chunk partials (packed), ratio test, write outputs -----
__global__ __launch_bounds__(256) void snn_reduce_kernel(const unsigned* __restrict__ pmin1,
                                                         const unsigned* __restrict__ pmin2,
                                                         const float* __restrict__ n1,
                                                         float* __restrict__ out) {
    const int i = blockIdx.x * 256 + threadIdx.x;
    unsigned a1 = 0xFFFFFFFFu, a2 = 0xFFFFFFFFu;
#pragma unroll
    for (int c = 0; c < NCHUNK; ++c) {
        const unsigned c1 = pmin1[(size_t)c * NB + i];
        const unsigned c2 = pmin2[(size_t)c * NB + i];
        const unsigned t = max(a1, c1);
        a1 = min(a1, c1);
        a2 = min(min(a2, c2), t);
    }
    const float v1 = __builtin_bit_cast(float, a1 & VMASK) - COFF; // n2 - 2*dot
    const float v2 = __builtin_bit_cast(float, a2 & VMASK) - COFF;
    const int idx = (int)(a1 & 0x1FFFu);
    const float nn = n1[i];
    const float d1 = sqrtf(fmaxf(nn + v1, 0.f));
    const float d2 = sqrtf(fmaxf(nn + v2, 0.f));
    const float ratio = d1 / d2;
    const bool mask = (ratio <= 0.8f); // NaN -> false, matches jnp
    out[i] = mask ? ratio : 0.0f;                      // match_dists (8192,1)
    out[NB + 2 * i] = mask ? (float)i : -1.0f;         // matches_idxs[:,0]
    out[NB + 2 * i + 1] = mask ? (float)idx : -1.0f;   // matches_idxs[:,1]
    out[3 * NB + i] = mask ? 1.0f : 0.0f;              // mask
}

extern "C" void kernel_launch(void* const* d_in, const int* in_sizes, int n_in,
                              void* d_out, int out_size, void* d_ws, size_t ws_size,
                              hipStream_t stream) {
    const float* desc1 = (const float*)d_in[0];
    const float* desc2 = (const float*)d_in[1];
    float* out = (float*)d_out;
    char* ws = (char*)d_ws;

    __bf16* d1b = (__bf16*)ws;                                   // 2 MB
    __bf16* d2b = (__bf16*)(ws + (size_t)2 * 1024 * 1024);       // 2 MB
    float* n1   = (float*)(ws + (size_t)4 * 1024 * 1024);        // 32 KB
    float* n2pc = (float*)(ws + (size_t)4 * 1024 * 1024 + 32768);// 32 KB
    unsigned* pmin1 = (unsigned*)(ws + (size_t)4 * 1024 * 1024 + 65536); // 512 KB
    unsigned* pmin2 = pmin1 + (size_t)NCHUNK * NB;                        // 512 KB

    conv_norm_kernel<<<2 * NB / 4, 256, 0, stream>>>(desc1, desc2, d1b, d2b, n1, n2pc);
    snn_main_kernel<<<dim3(NB / BM, NCHUNK), 256, 0, stream>>>(d1b, d2b, n2pc, pmin1, pmin2);
    snn_reduce_kernel<<<NB / 256, 256, 0, stream>>>(pmin1, pmin2, n1, out);
}

// Round 16
// 135.680 us; speedup vs baseline: 1.3516x; 1.3516x over previous
//
#include <hip/hip_runtime.h>

// DescriptorMatcher match_snn — R5 (resubmit x2; infra failures): R2 base + NCHUNK 32.
// R4 post-mortem: VGPR cap 32 starved ILP (all pipes idle at 68% occ) — reverted.
// R3 post-mortem: lambda-dbuf inflated VGPR 92 and regressed — reverted.
// R5 = R2 plain-loop structure (64 rows/wave, proven main~35us) + 1024 blocks
//      (4 blocks/CU) + launch_bounds(256,4) gentle cap (128 VGPR fits ~120 need).
// Core (proven, absmax 0.0): A pre-scaled by -2, acc init n2+COFF,
//      packed u = (bits(m') & 0xFFFFE000) | col ; top-2 via u32 min/max.

typedef __bf16 bf16x8 __attribute__((ext_vector_type(8)));
typedef __bf16 bf16x2 __attribute__((ext_vector_type(2)));
typedef float f32x4 __attribute__((ext_vector_type(4)));

#define NB 8192
#define DK 128
#define NCHUNK 32
#define CHUNK (NB / NCHUNK)   /* 256 cols per chunk */
#define JT (CHUNK / 16)       /* 16 col-tiles per chunk */
#define ROWS_PER_WAVE 64      /* 4 row-tiles of 16 */
#define BM 256                /* 4 waves per block */
#define COFF 512.0f           /* positivity offset for packed ordering */
#define VMASK 0xFFFFE000u     /* keep sign+exp+10 mantissa bits; low 13 = col */

// --- fused convert: desc1 -> -2*bf16, n1 raw ; desc2 -> bf16, n2+COFF ------
__global__ __launch_bounds__(256) void conv_norm_kernel(const float* __restrict__ desc1,
                                                        const float* __restrict__ desc2,
                                                        __bf16* __restrict__ d1b,
                                                        __bf16* __restrict__ d2b,
                                                        float* __restrict__ n1,
                                                        float* __restrict__ n2pc) {
    const int idx  = blockIdx.x * 4 + (threadIdx.x >> 6); // one wave per row
    const int lane = threadIdx.x & 63;
    const bool is2 = idx >= NB;
    const int row  = is2 ? idx - NB : idx;
    const float* src = is2 ? desc2 : desc1;
    const size_t off = (size_t)row * DK + lane * 2;
    const float2 v = *reinterpret_cast<const float2*>(src + off);
    float s = v.x * v.x + v.y * v.y;
    const float sc = is2 ? 1.0f : -2.0f;
    bf16x2 bp;
    bp[0] = (__bf16)(v.x * sc);
    bp[1] = (__bf16)(v.y * sc);
    *reinterpret_cast<bf16x2*>((is2 ? d2b : d1b) + off) = bp;
#pragma unroll
    for (int d = 1; d < 64; d <<= 1) s += __shfl_xor(s, d);
    if (lane == 0) {
        if (is2) n2pc[row] = s + COFF;
        else     n1[row] = s;
    }
}

// --- main: wave owns 64 rows x 256-col chunk; fused GEMM + packed top-2 ----
__global__ __launch_bounds__(256, 4) void snn_main_kernel(const __bf16* __restrict__ d1b,
                                                          const __bf16* __restrict__ d2b,
                                                          const float* __restrict__ n2pc,
                                                          unsigned* __restrict__ pmin1,
                                                          unsigned* __restrict__ pmin2) {
    const int lane    = threadIdx.x & 63;
    const int wid     = threadIdx.x >> 6;
    const int rowbase = blockIdx.x * BM + wid * ROWS_PER_WAVE;
    const int colbase = blockIdx.y * CHUNK;
    const int lrow    = lane & 15;
    const int lk      = (lane >> 4) * 8;

    // A fragments (row = lane&15, k = (lane>>4)*8 + b) — A is pre-scaled by -2
    bf16x8 afrag[4][4];
#pragma unroll
    for (int rt = 0; rt < 4; ++rt)
#pragma unroll
        for (int kk = 0; kk < 4; ++kk)
            afrag[rt][kk] = *reinterpret_cast<const bf16x8*>(
                d1b + (size_t)(rowbase + rt * 16 + lrow) * DK + kk * 32 + lk);

    unsigned p1[16], p2[16];
#pragma unroll
    for (int s = 0; s < 16; ++s) { p1[s] = 0xFFFFFFFFu; p2[s] = 0xFFFFFFFFu; }

    const __bf16* bbase = d2b + (size_t)(colbase + lrow) * DK + lk;
    const float* n2p = n2pc + colbase + lrow;
    const unsigned colv = colbase + lrow;

    for (int jt = 0; jt < JT; ++jt) {
        const __bf16* bp = bbase + (size_t)jt * 16 * DK;
        bf16x8 bfrag[4];
#pragma unroll
        for (int kk = 0; kk < 4; ++kk)
            bfrag[kk] = *reinterpret_cast<const bf16x8*>(bp + kk * 32);
        const float n2c = n2p[jt * 16];      // per-lane col constant (col = lane&15)
        const unsigned col = colv + jt * 16;
#pragma unroll
        for (int rt = 0; rt < 4; ++rt) {
            f32x4 acc = {n2c, n2c, n2c, n2c}; // acc exits loop = n2 + C - 2*dot
#pragma unroll
            for (int kk = 0; kk < 4; ++kk)
                acc = __builtin_amdgcn_mfma_f32_16x16x32_bf16(afrag[rt][kk], bfrag[kk], acc, 0, 0, 0);
            // C/D layout: col = lane&15, row = (lane>>4)*4 + e
#pragma unroll
            for (int e = 0; e < 4; ++e) {
                const unsigned u = (__builtin_bit_cast(unsigned, acc[e]) & VMASK) | col;
                const int s = rt * 4 + e;
                const unsigned t = max(p1[s], u);
                p1[s] = min(p1[s], u);
                p2[s] = min(p2[s], t);
            }
        }
    }

    // cross-lane top-2 merge within each 16-lane group (same rows, diff cols)
#pragma unroll
    for (int s = 0; s < 16; ++s) {
        unsigned a1 = p1[s], a2 = p2[s];
#pragma unroll
        for (int d = 1; d <= 8; d <<= 1) {
            const unsigned o1 = __shfl_xor(a1, d);
            const unsigned o2 = __shfl_xor(a2, d);
            const unsigned t = max(a1, o1);
            a1 = min(a1, o1);
            a2 = min(min(a2, o2), t);
        }
        if (lrow == 0) {
            const int row = rowbase + (s >> 2) * 16 + (lane >> 4) * 4 + (s & 3);
            const size_t off = (size_t)blockIdx.y * NB + row;
            pmin1[off] = a1;
            pmin2[off] = a2;
        }
    }
}

// --- phase 2: merge chunk partials (packed), ratio test, write outputs -----
__global__ __launch_bounds__(256) void snn_reduce_kernel(const unsigned* __restrict__ pmin1,
                                                         const unsigned* __restrict__ pmin2,
                                                         const float* __restrict__ n1,
                                                         float* __restrict__ out) {
    const int i = blockIdx.x * 256 + threadIdx.x;
    unsigned a1 = 0xFFFFFFFFu, a2 = 0xFFFFFFFFu;
#pragma unroll
    for (int c = 0; c < NCHUNK; ++c) {
        const unsigned c1 = pmin1[(size_t)c * NB + i];
        const unsigned c2 = pmin2[(size_t)c * NB + i];
        const unsigned t = max(a1, c1);
        a1 = min(a1, c1);
        a2 = min(min(a2, c2), t);
    }
    const float v1 = __builtin_bit_cast(float, a1 & VMASK) - COFF; // n2 - 2*dot
    const float v2 = __builtin_bit_cast(float, a2 & VMASK) - COFF;
    const int idx = (int)(a1 & 0x1FFFu);
    const float nn = n1[i];
    const float d1 = sqrtf(fmaxf(nn + v1, 0.f));
    const float d2 = sqrtf(fmaxf(nn + v2, 0.f));
    const float ratio = d1 / d2;
    const bool mask = (ratio <= 0.8f); // NaN -> false, matches jnp
    out[i] = mask ? ratio : 0.0f;                      // match_dists (8192,1)
    out[NB + 2 * i] = mask ? (float)i : -1.0f;         // matches_idxs[:,0]
    out[NB + 2 * i + 1] = mask ? (float)idx : -1.0f;   // matches_idxs[:,1]
    out[3 * NB + i] = mask ? 1.0f : 0.0f;              // mask
}

extern "C" void kernel_launch(void* const* d_in, const int* in_sizes, int n_in,
                              void* d_out, int out_size, void* d_ws, size_t ws_size,
                              hipStream_t stream) {
    const float* desc1 = (const float*)d_in[0];
    const float* desc2 = (const float*)d_in[1];
    float* out = (float*)d_out;
    char* ws = (char*)d_ws;

    __bf16* d1b = (__bf16*)ws;                                   // 2 MB
    __bf16* d2b = (__bf16*)(ws + (size_t)2 * 1024 * 1024);       // 2 MB
    float* n1   = (float*)(ws + (size_t)4 * 1024 * 1024);        // 32 KB
    float* n2pc = (float*)(ws + (size_t)4 * 1024 * 1024 + 32768);// 32 KB
    unsigned* pmin1 = (unsigned*)(ws + (size_t)4 * 1024 * 1024 + 65536); // 1 MB
    unsigned* pmin2 = pmin1 + (size_t)NCHUNK * NB;                        // 1 MB

    conv_norm_kernel<<<2 * NB / 4, 256, 0, stream>>>(desc1, desc2, d1b, d2b, n1, n2pc);
    snn_main_kernel<<<dim3(NB / BM, NCHUNK), 256, 0, stream>>>(d1b, d2b, n2pc, pmin1, pmin2);
    snn_reduce_kernel<<<NB / 256, 256, 0, stream>>>(pmin1, pmin2, n1, out);
}

// Round 17
// 119.570 us; speedup vs baseline: 1.5337x; 1.1347x over previous
//
#include <hip/hip_runtime.h>

// DescriptorMatcher match_snn — R6: R2 base + NCHUNK 32, NO launch_bounds cap.
// R5 post-mortem: (256,4) cap -> VGPR 64 vs ~130 working set -> ~200MB scratch
//   spill traffic/dispatch (FETCH 75MB, WRITE 133MB), HBM-bound 66us. Lesson:
//   launch_bounds 2nd arg under-allocates for this kernel (R4: 32, R5: 64) — dropped.
// R6 = R2 plain-loop (64 rows/wave, best measured ~33us) + 1024 blocks (4/CU),
//   uncapped VGPR (~100-110 expected, 4 waves/SIMD fit).
// Core (proven, absmax 0.0): A pre-scaled by -2, acc init n2+COFF,
//   packed u = (bits(m') & 0xFFFFE000) | col ; top-2 via u32 min/max.

typedef __bf16 bf16x8 __attribute__((ext_vector_type(8)));
typedef __bf16 bf16x2 __attribute__((ext_vector_type(2)));
typedef float f32x4 __attribute__((ext_vector_type(4)));

#define NB 8192
#define DK 128
#define NCHUNK 32
#define CHUNK (NB / NCHUNK)   /* 256 cols per chunk */
#define JT (CHUNK / 16)       /* 16 col-tiles per chunk */
#define ROWS_PER_WAVE 64      /* 4 row-tiles of 16 */
#define BM 256                /* 4 waves per block */
#define COFF 512.0f           /* positivity offset for packed ordering */
#define VMASK 0xFFFFE000u     /* keep sign+exp+10 mantissa bits; low 13 = col */

// --- fused convert: desc1 -> -2*bf16, n1 raw ; desc2 -> bf16, n2+COFF ------
__global__ __launch_bounds__(256) void conv_norm_kernel(const float* __restrict__ desc1,
                                                        const float* __restrict__ desc2,
                                                        __bf16* __restrict__ d1b,
                                                        __bf16* __restrict__ d2b,
                                                        float* __restrict__ n1,
                                                        float* __restrict__ n2pc) {
    const int idx  = blockIdx.x * 4 + (threadIdx.x >> 6); // one wave per row
    const int lane = threadIdx.x & 63;
    const bool is2 = idx >= NB;
    const int row  = is2 ? idx - NB : idx;
    const float* src = is2 ? desc2 : desc1;
    const size_t off = (size_t)row * DK + lane * 2;
    const float2 v = *reinterpret_cast<const float2*>(src + off);
    float s = v.x * v.x + v.y * v.y;
    const float sc = is2 ? 1.0f : -2.0f;
    bf16x2 bp;
    bp[0] = (__bf16)(v.x * sc);
    bp[1] = (__bf16)(v.y * sc);
    *reinterpret_cast<bf16x2*>((is2 ? d2b : d1b) + off) = bp;
#pragma unroll
    for (int d = 1; d < 64; d <<= 1) s += __shfl_xor(s, d);
    if (lane == 0) {
        if (is2) n2pc[row] = s + COFF;
        else     n1[row] = s;
    }
}

// --- main: wave owns 64 rows x 256-col chunk; fused GEMM + packed top-2 ----
__global__ __launch_bounds__(256) void snn_main_kernel(const __bf16* __restrict__ d1b,
                                                       const __bf16* __restrict__ d2b,
                                                       const float* __restrict__ n2pc,
                                                       unsigned* __restrict__ pmin1,
                                                       unsigned* __restrict__ pmin2) {
    const int lane    = threadIdx.x & 63;
    const int wid     = threadIdx.x >> 6;
    const int rowbase = blockIdx.x * BM + wid * ROWS_PER_WAVE;
    const int colbase = blockIdx.y * CHUNK;
    const int lrow    = lane & 15;
    const int lk      = (lane >> 4) * 8;

    // A fragments (row = lane&15, k = (lane>>4)*8 + b) — A is pre-scaled by -2
    bf16x8 afrag[4][4];
#pragma unroll
    for (int rt = 0; rt < 4; ++rt)
#pragma unroll
        for (int kk = 0; kk < 4; ++kk)
            afrag[rt][kk] = *reinterpret_cast<const bf16x8*>(
                d1b + (size_t)(rowbase + rt * 16 + lrow) * DK + kk * 32 + lk);

    unsigned p1[16], p2[16];
#pragma unroll
    for (int s = 0; s < 16; ++s) { p1[s] = 0xFFFFFFFFu; p2[s] = 0xFFFFFFFFu; }

    const __bf16* bbase = d2b + (size_t)(colbase + lrow) * DK + lk;
    const float* n2p = n2pc + colbase + lrow;
    const unsigned colv = colbase + lrow;

    for (int jt = 0; jt < JT; ++jt) {
        const __bf16* bp = bbase + (size_t)jt * 16 * DK;
        bf16x8 bfrag[4];
#pragma unroll
        for (int kk = 0; kk < 4; ++kk)
            bfrag[kk] = *reinterpret_cast<const bf16x8*>(bp + kk * 32);
        const float n2c = n2p[jt * 16];      // per-lane col constant (col = lane&15)
        const unsigned col = colv + jt * 16;
#pragma unroll
        for (int rt = 0; rt < 4; ++rt) {
            f32x4 acc = {n2c, n2c, n2c, n2c}; // acc exits loop = n2 + C - 2*dot
#pragma unroll
            for (int kk = 0; kk < 4; ++kk)
                acc = __builtin_amdgcn_mfma_f32_16x16x32_bf16(afrag[rt][kk], bfrag[kk], acc, 0, 0, 0);
            // C/D layout: col = lane&15, row = (lane>>4)*4 + e
#pragma unroll
            for (int e = 0; e < 4; ++e) {
                const unsigned u = (__builtin_bit_cast(unsigned, acc[e]) & VMASK) | col;
                const int s = rt * 4 + e;
                const unsigned t = max(p1[s], u);
                p1[s] = min(p1[s], u);
                p2[s] = min(p2[s], t);
            }
        }
    }

    // cross-lane top-2 merge within each 16-lane group (same rows, diff cols)
#pragma unroll
    for (int s = 0; s < 16; ++s) {
        unsigned a1 = p1[s], a2 = p2[s];
#pragma unroll
        for (int d = 1; d <= 8; d <<= 1) {
            const unsigned o1 = __shfl_xor(a1, d);
            const unsigned o2 = __shfl_xor(a2, d);
            const unsigned t = max(a1, o1);
            a1 = min(a1, o1);
            a2 = min(min(a2, o2), t);
        }
        if (lrow == 0) {
            const int row = rowbase + (s >> 2) * 16 + (lane >> 4) * 4 + (s & 3);
            const size_t off = (size_t)blockIdx.y * NB + row;
            pmin1[off] = a1;
            pmin2[off] = a2;
        }
    }
}

// --- phase 2: merge chunk partials (packed), ratio test, write outputs -----
__global__ __launch_bounds__(256) void snn_reduce_kernel(const unsigned* __restrict__ pmin1,
                                                         const unsigned* __restrict__ pmin2,
                                                         const float* __restrict__ n1,
                                                         float* __restrict__ out) {
    const int i = blockIdx.x * 256 + threadIdx.x;
    unsigned a1 = 0xFFFFFFFFu, a2 = 0xFFFFFFFFu;
#pragma unroll
    for (int c = 0; c < NCHUNK; ++c) {
        const unsigned c1 = pmin1[(size_t)c * NB + i];
        const unsigned c2 = pmin2[(size_t)c * NB + i];
        const unsigned t = max(a1, c1);
        a1 = min(a1, c1);
        a2 = min(min(a2, c2), t);
    }
    const float v1 = __builtin_bit_cast(float, a1 & VMASK) - COFF; // n2 - 2*dot
    const float v2 = __builtin_bit_cast(float, a2 & VMASK) - COFF;
    const int idx = (int)(a1 & 0x1FFFu);
    const float nn = n1[i];
    const float d1 = sqrtf(fmaxf(nn + v1, 0.f));
    const float d2 = sqrtf(fmaxf(nn + v2, 0.f));
    const float ratio = d1 / d2;
    const bool mask = (ratio <= 0.8f); // NaN -> false, matches jnp
    out[i] = mask ? ratio : 0.0f;                      // match_dists (8192,1)
    out[NB + 2 * i] = mask ? (float)i : -1.0f;         // matches_idxs[:,0]
    out[NB + 2 * i + 1] = mask ? (float)idx : -1.0f;   // matches_idxs[:,1]
    out[3 * NB + i] = mask ? 1.0f : 0.0f;              // mask
}

extern "C" void kernel_launch(void* const* d_in, const int* in_sizes, int n_in,
                              void* d_out, int out_size, void* d_ws, size_t ws_size,
                              hipStream_t stream) {
    const float* desc1 = (const float*)d_in[0];
    const float* desc2 = (const float*)d_in[1];
    float* out = (float*)d_out;
    char* ws = (char*)d_ws;

    __bf16* d1b = (__bf16*)ws;                                   // 2 MB
    __bf16* d2b = (__bf16*)(ws + (size_t)2 * 1024 * 1024);       // 2 MB
    float* n1   = (float*)(ws + (size_t)4 * 1024 * 1024);        // 32 KB
    float* n2pc = (float*)(ws + (size_t)4 * 1024 * 1024 + 32768);// 32 KB
    unsigned* pmin1 = (unsigned*)(ws + (size_t)4 * 1024 * 1024 + 65536); // 1 MB
    unsigned* pmin2 = pmin1 + (size_t)NCHUNK * NB;                        // 1 MB

    conv_norm_kernel<<<2 * NB / 4, 256, 0, stream>>>(desc1, desc2, d1b, d2b, n1, n2pc);
    snn_main_kernel<<<dim3(NB / BM, NCHUNK), 256, 0, stream>>>(d1b, d2b, n2pc, pmin1, pmin2);
    snn_reduce_kernel<<<NB / 256, 256, 0, stream>>>(pmin1, pmin2, n1, out);
}

// Round 18
// 106.983 us; speedup vs baseline: 1.7141x; 1.1177x over previous
//
#include <hip/hip_runtime.h>

// DescriptorMatcher match_snn — R7: NCHUNK 16 (measured best) + 2-deep B-load batch.
// Ledger: NCHUNK16 main~33us; NCHUNK32 main 48-50us (R3 lambda ~= R6 plain -> the
//   chunk split was the regression, not the lambda). launch_bounds 2nd arg spills
//   (R4 cap32, R5 cap64 -> 200MB scratch) — never cap again.
// R7 delta: jt-loop unrolled x2, all 8 B dwordx4 loads issued before compute
//   (one L2/L3 latency window covers two tiles). Straight-line, no lambdas.
// Core (proven, absmax 0.0): A pre-scaled by -2, acc init n2+COFF,
//   packed u = (bits(m') & 0xFFFFE000) | col ; top-2 via u32 min/max.

typedef __bf16 bf16x8 __attribute__((ext_vector_type(8)));
typedef __bf16 bf16x2 __attribute__((ext_vector_type(2)));
typedef float f32x4 __attribute__((ext_vector_type(4)));

#define NB 8192
#define DK 128
#define NCHUNK 16
#define CHUNK (NB / NCHUNK)   /* 512 cols per chunk */
#define JT (CHUNK / 16)       /* 32 col-tiles per chunk */
#define ROWS_PER_WAVE 64      /* 4 row-tiles of 16 */
#define BM 256                /* 4 waves per block */
#define COFF 512.0f           /* positivity offset for packed ordering */
#define VMASK 0xFFFFE000u     /* keep sign+exp+10 mantissa bits; low 13 = col */

// --- fused convert: desc1 -> -2*bf16, n1 raw ; desc2 -> bf16, n2+COFF ------
__global__ __launch_bounds__(256) void conv_norm_kernel(const float* __restrict__ desc1,
                                                        const float* __restrict__ desc2,
                                                        __bf16* __restrict__ d1b,
                                                        __bf16* __restrict__ d2b,
                                                        float* __restrict__ n1,
                                                        float* __restrict__ n2pc) {
    const int idx  = blockIdx.x * 4 + (threadIdx.x >> 6); // one wave per row
    const int lane = threadIdx.x & 63;
    const bool is2 = idx >= NB;
    const int row  = is2 ? idx - NB : idx;
    const float* src = is2 ? desc2 : desc1;
    const size_t off = (size_t)row * DK + lane * 2;
    const float2 v = *reinterpret_cast<const float2*>(src + off);
    float s = v.x * v.x + v.y * v.y;
    const float sc = is2 ? 1.0f : -2.0f;
    bf16x2 bp;
    bp[0] = (__bf16)(v.x * sc);
    bp[1] = (__bf16)(v.y * sc);
    *reinterpret_cast<bf16x2*>((is2 ? d2b : d1b) + off) = bp;
#pragma unroll
    for (int d = 1; d < 64; d <<= 1) s += __shfl_xor(s, d);
    if (lane == 0) {
        if (is2) n2pc[row] = s + COFF;
        else     n1[row] = s;
    }
}

// --- main: wave owns 64 rows x 512-col chunk; fused GEMM + packed top-2 ----
__global__ __launch_bounds__(256) void snn_main_kernel(const __bf16* __restrict__ d1b,
                                                       const __bf16* __restrict__ d2b,
                                                       const float* __restrict__ n2pc,
                                                       unsigned* __restrict__ pmin1,
                                                       unsigned* __restrict__ pmin2) {
    const int lane    = threadIdx.x & 63;
    const int wid     = threadIdx.x >> 6;
    const int rowbase = blockIdx.x * BM + wid * ROWS_PER_WAVE;
    const int colbase = blockIdx.y * CHUNK;
    const int lrow    = lane & 15;
    const int lk      = (lane >> 4) * 8;

    // A fragments (row = lane&15, k = (lane>>4)*8 + b) — A is pre-scaled by -2
    bf16x8 afrag[4][4];
#pragma unroll
    for (int rt = 0; rt < 4; ++rt)
#pragma unroll
        for (int kk = 0; kk < 4; ++kk)
            afrag[rt][kk] = *reinterpret_cast<const bf16x8*>(
                d1b + (size_t)(rowbase + rt * 16 + lrow) * DK + kk * 32 + lk);

    unsigned p1[16], p2[16];
#pragma unroll
    for (int s = 0; s < 16; ++s) { p1[s] = 0xFFFFFFFFu; p2[s] = 0xFFFFFFFFu; }

    const __bf16* bbase = d2b + (size_t)(colbase + lrow) * DK + lk;
    const float* n2p = n2pc + colbase + lrow;
    const unsigned colv = colbase + lrow;

    for (int jt = 0; jt < JT; jt += 2) {
        // issue ALL 8 B-tile loads (two tiles) before any compute — one
        // latency window covers both tiles (MLP, not a cap/lambda in sight)
        const __bf16* bp0 = bbase + (size_t)jt * 16 * DK;
        const __bf16* bp1 = bp0 + (size_t)16 * DK;
        bf16x8 b0[4], b1[4];
#pragma unroll
        for (int kk = 0; kk < 4; ++kk)
            b0[kk] = *reinterpret_cast<const bf16x8*>(bp0 + kk * 32);
#pragma unroll
        for (int kk = 0; kk < 4; ++kk)
            b1[kk] = *reinterpret_cast<const bf16x8*>(bp1 + kk * 32);
        const float n2c0 = n2p[jt * 16];
        const float n2c1 = n2p[jt * 16 + 16];
        const unsigned col0 = colv + jt * 16;
        const unsigned col1 = col0 + 16;

#pragma unroll
        for (int rt = 0; rt < 4; ++rt) {
            f32x4 acc = {n2c0, n2c0, n2c0, n2c0}; // exits = n2 + C - 2*dot
#pragma unroll
            for (int kk = 0; kk < 4; ++kk)
                acc = __builtin_amdgcn_mfma_f32_16x16x32_bf16(afrag[rt][kk], b0[kk], acc, 0, 0, 0);
            // C/D layout: col = lane&15, row = (lane>>4)*4 + e
#pragma unroll
            for (int e = 0; e < 4; ++e) {
                const unsigned u = (__builtin_bit_cast(unsigned, acc[e]) & VMASK) | col0;
                const int s = rt * 4 + e;
                const unsigned t = max(p1[s], u);
                p1[s] = min(p1[s], u);
                p2[s] = min(p2[s], t);
            }
        }
#pragma unroll
        for (int rt = 0; rt < 4; ++rt) {
            f32x4 acc = {n2c1, n2c1, n2c1, n2c1};
#pragma unroll
            for (int kk = 0; kk < 4; ++kk)
                acc = __builtin_amdgcn_mfma_f32_16x16x32_bf16(afrag[rt][kk], b1[kk], acc, 0, 0, 0);
#pragma unroll
            for (int e = 0; e < 4; ++e) {
                const unsigned u = (__builtin_bit_cast(unsigned, acc[e]) & VMASK) | col1;
                const int s = rt * 4 + e;
                const unsigned t = max(p1[s], u);
                p1[s] = min(p1[s], u);
                p2[s] = min(p2[s], t);
            }
        }
    }

    // cross-lane top-2 merge within each 16-lane group (same rows, diff cols)
#pragma unroll
    for (int s = 0; s < 16; ++s) {
        unsigned a1 = p1[s], a2 = p2[s];
#pragma unroll
        for (int d = 1; d <= 8; d <<= 1) {
            const unsigned o1 = __shfl_xor(a1, d);
            const unsigned o2 = __shfl_xor(a2, d);
            const unsigned t = max(a1, o1);
            a1 = min(a1, o1);
            a2 = min(min(a2, o2), t);
        }
        if (lrow == 0) {
            const int row = rowbase + (s >> 2) * 16 + (lane >> 4) * 4 + (s & 3);
            const size_t off = (size_t)blockIdx.y * NB + row;
            pmin1[off] = a1;
            pmin2[off] = a2;
        }
    }
}

// --- phase 2: merge chunk partials (packed), ratio test, write outputs -----
__global__ __launch_bounds__(256) void snn_reduce_kernel(const unsigned* __restrict__ pmin1,
                                                         const unsigned* __restrict__ pmin2,
                                                         const float* __restrict__ n1,
                                                         float* __restrict__ out) {
    const int i = blockIdx.x * 256 + threadIdx.x;
    unsigned a1 = 0xFFFFFFFFu, a2 = 0xFFFFFFFFu;
#pragma unroll
    for (int c = 0; c < NCHUNK; ++c) {
        const unsigned c1 = pmin1[(size_t)c * NB + i];
        const unsigned c2 = pmin2[(size_t)c * NB + i];
        const unsigned t = max(a1, c1);
        a1 = min(a1, c1);
        a2 = min(min(a2, c2), t);
    }
    const float v1 = __builtin_bit_cast(float, a1 & VMASK) - COFF; // n2 - 2*dot
    const float v2 = __builtin_bit_cast(float, a2 & VMASK) - COFF;
    const int idx = (int)(a1 & 0x1FFFu);
    const float nn = n1[i];
    const float d1 = sqrtf(fmaxf(nn + v1, 0.f));
    const float d2 = sqrtf(fmaxf(nn + v2, 0.f));
    const float ratio = d1 / d2;
    const bool mask = (ratio <= 0.8f); // NaN -> false, matches jnp
    out[i] = mask ? ratio : 0.0f;                      // match_dists (8192,1)
    out[NB + 2 * i] = mask ? (float)i : -1.0f;         // matches_idxs[:,0]
    out[NB + 2 * i + 1] = mask ? (float)idx : -1.0f;   // matches_idxs[:,1]
    out[3 * NB + i] = mask ? 1.0f : 0.0f;              // mask
}

extern "C" void kernel_launch(void* const* d_in, const int* in_sizes, int n_in,
                              void* d_out, int out_size, void* d_ws, size_t ws_size,
                              hipStream_t stream) {
    const float* desc1 = (const float*)d_in[0];
    const float* desc2 = (const float*)d_in[1];
    float* out = (float*)d_out;
    char* ws = (char*)d_ws;

    __bf16* d1b = (__bf16*)ws;                                   // 2 MB
    __bf16* d2b = (__bf16*)(ws + (size_t)2 * 1024 * 1024);       // 2 MB
    float* n1   = (float*)(ws + (size_t)4 * 1024 * 1024);        // 32 KB
    float* n2pc = (float*)(ws + (size_t)4 * 1024 * 1024 + 32768);// 32 KB
    unsigned* pmin1 = (unsigned*)(ws + (size_t)4 * 1024 * 1024 + 65536); // 512 KB
    unsigned* pmin2 = pmin1 + (size_t)NCHUNK * NB;                        // 512 KB

    conv_norm_kernel<<<2 * NB / 4, 256, 0, stream>>>(desc1, desc2, d1b, d2b, n1, n2pc);
    snn_main_kernel<<<dim3(NB / BM, NCHUNK), 256, 0, stream>>>(d1b, d2b, n2pc, pmin1, pmin2);
    snn_reduce_kernel<<<NB / 256, 256, 0, stream>>>(pmin1, pmin2, n1, out);
}